// Round 2
// baseline (160.861 us; speedup 1.0000x reference)
//
#include <hip/hip_runtime.h>
#include <math.h>

#define B_ 256
#define S_ 50
#define K_ 20
#define D_ 128
#define G3 384  // 3*D
#define KSPLIT 4

// ---------------------------------------------------------------------------
// Kernel A: basket pooling + gx = pooled @ w_ih^T + b_ih
// grid = B_*KSPLIT blocks, 384 threads. Thread j holds w_ih[j][0:128] in VGPRs
// (statically indexed -> registers). pooled broadcast via LDS float4 reads.
// ---------------------------------------------------------------------------
__global__ __launch_bounds__(384) void pool_gx_kernel(
    const int* __restrict__ items, const int* __restrict__ basket_len,
    const int* __restrict__ lengths, const float* __restrict__ encode,
    const float* __restrict__ w_ih, const float* __restrict__ b_ih,
    float* __restrict__ gx)
{
    const int b  = blockIdx.x / KSPLIT;
    const int s0 = blockIdx.x % KSPLIT;
    const int len = lengths[b];
    const int j = threadIdx.x;  // 0..383

    // weight row -> registers (one-time, 196KB/block from L2)
    float w[128];
    const float4* wrow = reinterpret_cast<const float4*>(w_ih + j * D_);
    #pragma unroll
    for (int q = 0; q < 32; ++q) {
        float4 v = wrow[q];
        w[4*q+0] = v.x; w[4*q+1] = v.y; w[4*q+2] = v.z; w[4*q+3] = v.w;
    }
    const float bias = b_ih[j];

    __shared__ float  part[3][128];
    __shared__ float4 pooled4[32];
    const int g = j >> 7;     // 0..2  (uniform per wave: waves 0,1->0; 2,3->1; 4,5->2)
    const int d = j & 127;

    for (int s = s0; s < len; s += KSPLIT) {
        const int  blen = basket_len[b * S_ + s];
        const int* it   = items + (b * S_ + s) * K_;
        // partial gather-sum: group g handles k = g, g+3, ...
        float p = 0.f;
        for (int k = g; k < blen; k += 3)
            p += encode[(long)it[k] * D_ + d];
        part[g][d] = p;
        __syncthreads();
        if (j < 128) {
            float pv = (part[0][j] + part[1][j] + part[2][j]) / (float)blen;
            ((float*)pooled4)[j] = pv;
        }
        __syncthreads();
        // gx[j] = bias + dot(pooled, w_row_j)
        float acc = bias;
        #pragma unroll
        for (int q = 0; q < 32; ++q) {
            float4 hv = pooled4[q];
            acc = fmaf(hv.x, w[4*q+0], acc);
            acc = fmaf(hv.y, w[4*q+1], acc);
            acc = fmaf(hv.z, w[4*q+2], acc);
            acc = fmaf(hv.w, w[4*q+3], acc);
        }
        gx[((long)b * S_ + s) * G3 + j] = acc;
        __syncthreads();  // protect part/pooled4 before next iteration overwrites
    }
}

// ---------------------------------------------------------------------------
// Kernel B: sequential GRU. grid = B_ blocks (one per batch row), 384 threads.
// Thread j holds w_hh[j][0:128] in VGPRs; h lives in LDS (512B broadcast).
// ---------------------------------------------------------------------------
__global__ __launch_bounds__(384) void gru_kernel(
    const int* __restrict__ lengths, const float* __restrict__ w_hh,
    const float* __restrict__ b_hh, const float* __restrict__ h0,
    const float* __restrict__ gx, float* __restrict__ out)
{
    const int b   = blockIdx.x;
    const int len = lengths[b];
    const int j   = threadIdx.x;

    float w[128];
    const float4* wrow = reinterpret_cast<const float4*>(w_hh + j * D_);
    #pragma unroll
    for (int q = 0; q < 32; ++q) {
        float4 v = wrow[q];
        w[4*q+0] = v.x; w[4*q+1] = v.y; w[4*q+2] = v.z; w[4*q+3] = v.w;
    }
    const float bias = b_hh[j];

    __shared__ float4 h4[32];     // hidden state, 128 f32
    __shared__ float  gh[G3];
    if (j < 128) ((float*)h4)[j] = h0[b * D_ + j];
    __syncthreads();

    float* ys = out;                          // (B,S,D)
    float* hu = out + (long)B_ * S_ * D_;     // (B,D)

    for (int s = 0; s < len; ++s) {
        // gh[j] = bias + dot(h, w_hh_row_j)
        float acc = bias;
        #pragma unroll
        for (int q = 0; q < 32; ++q) {
            float4 hv = h4[q];
            acc = fmaf(hv.x, w[4*q+0], acc);
            acc = fmaf(hv.y, w[4*q+1], acc);
            acc = fmaf(hv.z, w[4*q+2], acc);
            acc = fmaf(hv.w, w[4*q+3], acc);
        }
        gh[j] = acc;
        __syncthreads();
        if (j < 128) {
            const float* gxp = gx + ((long)b * S_ + s) * G3;
            float gxr = gxp[j], gxz = gxp[128 + j], gxn = gxp[256 + j];
            float ghr = gh[j], ghz = gh[128 + j], ghn = gh[256 + j];
            float r = 1.f / (1.f + expf(-(gxr + ghr)));
            float z = 1.f / (1.f + expf(-(gxz + ghz)));
            float n = tanhf(gxn + r * ghn);
            float hprev = ((float*)h4)[j];
            float hn = (1.f - z) * n + z * hprev;
            ys[((long)b * S_ + s) * D_ + j] = hn;   // s < len  =>  mask > 0
            ((float*)h4)[j] = hn;
        }
        __syncthreads();
    }
    // masked tail: y = 0; final hidden
    if (j < 128) {
        hu[b * D_ + j] = ((float*)h4)[j];
        for (int s = len; s < S_; ++s)
            ys[((long)b * S_ + s) * D_ + j] = 0.f;
    }
}

extern "C" void kernel_launch(void* const* d_in, const int* in_sizes, int n_in,
                              void* d_out, int out_size, void* d_ws, size_t ws_size,
                              hipStream_t stream) {
    const int*   items      = (const int*)d_in[0];
    const int*   basket_len = (const int*)d_in[1];
    const int*   lengths    = (const int*)d_in[2];
    const float* encode     = (const float*)d_in[3];
    const float* w_ih       = (const float*)d_in[4];
    const float* w_hh       = (const float*)d_in[5];
    const float* b_ih       = (const float*)d_in[6];
    const float* b_hh       = (const float*)d_in[7];
    const float* h0         = (const float*)d_in[8];
    float* out = (float*)d_out;
    float* gx  = (float*)d_ws;   // B*S*384 f32 = 19.7 MB

    pool_gx_kernel<<<B_ * KSPLIT, 384, 0, stream>>>(
        items, basket_len, lengths, encode, w_ih, b_ih, gx);
    gru_kernel<<<B_, 384, 0, stream>>>(
        lengths, w_hh, b_hh, h0, gx, out);
}

// Round 7
// 116.810 us; speedup vs baseline: 1.3771x; 1.3771x over previous
//
#include <hip/hip_runtime.h>
#include <math.h>

#define B_ 256
#define S_ 50
#define K_ 20
#define D_ 128
#define G3 384          // 3*D
#define M_  (B_ * S_)   // 12800 (b,s) rows

// ---------------------------------------------------------------------------
// Kernel P: basket pooling. 256 thr/block = two (b,s) rows; 6400 blocks.
// Gather latency hidden by ~50 blocks/CU of TLP. Coalesced 512B row reads.
// ---------------------------------------------------------------------------
__global__ __launch_bounds__(256) void pool_kernel(
    const int* __restrict__ items, const int* __restrict__ basket_len,
    const int* __restrict__ lengths, const float* __restrict__ encode,
    float* __restrict__ pooled)
{
    const int tid  = threadIdx.x;
    const int pair = tid >> 7;
    const int d    = tid & 127;
    const int m    = blockIdx.x * 2 + pair;   // (b,s) row id
    const int b    = m / S_;
    const int s    = m % S_;
    const int len  = lengths[b];

    float p = 0.f;
    if (s < len) {
        const int  blen = basket_len[m];
        const int* it   = items + m * K_;
        for (int k = 0; k < blen; ++k)
            p += encode[(long)it[k] * D_ + d];
        p /= (float)blen;
    }
    pooled[m * D_ + d] = p;
}

// ---------------------------------------------------------------------------
// Kernel G: gx = pooled @ w_ih^T + b_ih. M=12800, N=384, K=128.
// Tiled f32 GEMM: block tile 64M x 128N, Kt=32, 256 thr, 4x8 per-thread tile.
// Weights stream L2->LDS with 64-row reuse (no per-thread residency needed).
// ---------------------------------------------------------------------------
__global__ __launch_bounds__(256) void gx_gemm_kernel(
    const float* __restrict__ pooled, const float* __restrict__ w_ih,
    const float* __restrict__ b_ih, float* __restrict__ gx)
{
    __shared__ float As[32][64];    // [k][m]
    __shared__ float Bs[32][128];   // [k][n]

    const int tid = threadIdx.x;
    const int bm  = blockIdx.x % 200;       // consecutive blocks share w-tile (L2)
    const int bn  = blockIdx.x / 200;       // 0..2
    const int m0  = bm * 64;
    const int n0  = bn * 128;
    const int tx  = tid & 15;               // -> N
    const int ty  = tid >> 4;               // -> M

    float acc[4][8] = {};

    for (int kt = 0; kt < 128; kt += 32) {
        // stage A: 64 rows x 32 k = 512 float4
        #pragma unroll
        for (int i = 0; i < 2; ++i) {
            int idx = tid + 256 * i;        // 0..511
            int r = idx >> 3, c = idx & 7;
            float4 v = *reinterpret_cast<const float4*>(
                pooled + (m0 + r) * 128 + kt + c * 4);
            As[c*4+0][r] = v.x; As[c*4+1][r] = v.y;
            As[c*4+2][r] = v.z; As[c*4+3][r] = v.w;
        }
        // stage B: 128 rows x 32 k = 1024 float4
        #pragma unroll
        for (int i = 0; i < 4; ++i) {
            int idx = tid + 256 * i;        // 0..1023
            int r = idx >> 3, c = idx & 7;
            float4 v = *reinterpret_cast<const float4*>(
                w_ih + (n0 + r) * 128 + kt + c * 4);
            Bs[c*4+0][r] = v.x; Bs[c*4+1][r] = v.y;
            Bs[c*4+2][r] = v.z; Bs[c*4+3][r] = v.w;
        }
        __syncthreads();

        #pragma unroll
        for (int k = 0; k < 32; ++k) {
            float4 a  = *reinterpret_cast<const float4*>(&As[k][ty * 4]);
            float4 b0 = *reinterpret_cast<const float4*>(&Bs[k][tx * 8]);
            float4 b1 = *reinterpret_cast<const float4*>(&Bs[k][tx * 8 + 4]);
            float av[4] = {a.x, a.y, a.z, a.w};
            float bv[8] = {b0.x, b0.y, b0.z, b0.w, b1.x, b1.y, b1.z, b1.w};
            #pragma unroll
            for (int mi = 0; mi < 4; ++mi)
                #pragma unroll
                for (int ni = 0; ni < 8; ++ni)
                    acc[mi][ni] = fmaf(av[mi], bv[ni], acc[mi][ni]);
        }
        __syncthreads();
    }

    // epilogue: + bias, write
    float bias[8];
    #pragma unroll
    for (int ni = 0; ni < 8; ++ni) bias[ni] = b_ih[n0 + tx * 8 + ni];
    #pragma unroll
    for (int mi = 0; mi < 4; ++mi) {
        const int row = m0 + ty * 4 + mi;
        float4 o0, o1;
        o0.x = acc[mi][0] + bias[0]; o0.y = acc[mi][1] + bias[1];
        o0.z = acc[mi][2] + bias[2]; o0.w = acc[mi][3] + bias[3];
        o1.x = acc[mi][4] + bias[4]; o1.y = acc[mi][5] + bias[5];
        o1.z = acc[mi][6] + bias[6]; o1.w = acc[mi][7] + bias[7];
        float* dst = gx + (long)row * G3 + n0 + tx * 8;
        *reinterpret_cast<float4*>(dst)     = o0;
        *reinterpret_cast<float4*>(dst + 4) = o1;
    }
}

// ---------------------------------------------------------------------------
// Kernel B: sequential GRU. 256 blocks (one per batch row), 384 threads.
// w_hh rows pinned in VGPRs via asm (prevents load-sinking observed in R2:
// VGPR_Count=80 proved the compiler re-read weights from L2 every step).
// ---------------------------------------------------------------------------
__global__ __launch_bounds__(384, 1) void gru_kernel(
    const int* __restrict__ lengths, const float* __restrict__ w_hh,
    const float* __restrict__ b_hh, const float* __restrict__ h0,
    const float* __restrict__ gx, float* __restrict__ out)
{
    const int b   = blockIdx.x;
    const int len = lengths[b];
    const int j   = threadIdx.x;

    float w[128];
    const float4* wrow = reinterpret_cast<const float4*>(w_hh + j * D_);
    #pragma unroll
    for (int q = 0; q < 32; ++q) {
        float4 v = wrow[q];
        w[4*q+0] = v.x; w[4*q+1] = v.y; w[4*q+2] = v.z; w[4*q+3] = v.w;
    }
    // pin: force residency, forbid sinking the loads into the s-loop
    #pragma unroll
    for (int i = 0; i < 128; ++i) asm volatile("" : "+v"(w[i]));

    const float bias = b_hh[j];

    __shared__ float4 h4[32];     // hidden state, 128 f32
    __shared__ float  gh[G3];
    if (j < 128) ((float*)h4)[j] = h0[b * D_ + j];
    __syncthreads();

    float* ys = out;                          // (B,S,D)
    float* hu = out + (long)B_ * S_ * D_;     // (B,D)

    for (int s = 0; s < len; ++s) {
        // issue gx loads early (independent of h) to overlap with the dot
        float gxr = 0.f, gxz = 0.f, gxn = 0.f;
        if (j < 128) {
            const float* gxp = gx + ((long)b * S_ + s) * G3;
            gxr = gxp[j]; gxz = gxp[128 + j]; gxn = gxp[256 + j];
        }
        // gh[j] = bias + dot(h, w_hh_row_j)
        float acc = bias;
        #pragma unroll
        for (int q = 0; q < 32; ++q) {
            float4 hv = h4[q];
            acc = fmaf(hv.x, w[4*q+0], acc);
            acc = fmaf(hv.y, w[4*q+1], acc);
            acc = fmaf(hv.z, w[4*q+2], acc);
            acc = fmaf(hv.w, w[4*q+3], acc);
        }
        gh[j] = acc;
        __syncthreads();
        if (j < 128) {
            float ghr = gh[j], ghz = gh[128 + j], ghn = gh[256 + j];
            float r = 1.f / (1.f + expf(-(gxr + ghr)));
            float z = 1.f / (1.f + expf(-(gxz + ghz)));
            float n = tanhf(gxn + r * ghn);
            float hprev = ((float*)h4)[j];
            float hn = (1.f - z) * n + z * hprev;
            ys[((long)b * S_ + s) * D_ + j] = hn;
            ((float*)h4)[j] = hn;
        }
        __syncthreads();
    }
    if (j < 128) {
        hu[b * D_ + j] = ((float*)h4)[j];
        for (int s = len; s < S_; ++s)
            ys[((long)b * S_ + s) * D_ + j] = 0.f;
    }
}

extern "C" void kernel_launch(void* const* d_in, const int* in_sizes, int n_in,
                              void* d_out, int out_size, void* d_ws, size_t ws_size,
                              hipStream_t stream) {
    const int*   items      = (const int*)d_in[0];
    const int*   basket_len = (const int*)d_in[1];
    const int*   lengths    = (const int*)d_in[2];
    const float* encode     = (const float*)d_in[3];
    const float* w_ih       = (const float*)d_in[4];
    const float* w_hh       = (const float*)d_in[5];
    const float* b_ih       = (const float*)d_in[6];
    const float* b_hh       = (const float*)d_in[7];
    const float* h0         = (const float*)d_in[8];
    float* out = (float*)d_out;

    float* gx     = (float*)d_ws;                       // 12800*384 f32 = 19.66 MB
    float* pooled = gx + (long)M_ * G3;                 // 12800*128 f32 =  6.55 MB

    pool_kernel<<<M_ / 2, 256, 0, stream>>>(
        items, basket_len, lengths, encode, pooled);
    gx_gemm_kernel<<<600, 256, 0, stream>>>(
        pooled, w_ih, b_ih, gx);
    gru_kernel<<<B_, 384, 0, stream>>>(
        lengths, w_hh, b_hh, h0, gx, out);
}

// Round 8
// 116.273 us; speedup vs baseline: 1.3835x; 1.0046x over previous
//
#include <hip/hip_runtime.h>
#include <math.h>

#define B_ 256
#define S_ 50
#define K_ 20
#define D_ 128
#define G3 384          // 3*D
#define M_  (B_ * S_)   // 12800 (b,s) rows

// ---------------------------------------------------------------------------
// Kernel P: basket pooling. 256 thr/block = two (b,s) rows; 6400 blocks.
// ---------------------------------------------------------------------------
__global__ __launch_bounds__(256) void pool_kernel(
    const int* __restrict__ items, const int* __restrict__ basket_len,
    const int* __restrict__ lengths, const float* __restrict__ encode,
    float* __restrict__ pooled)
{
    const int tid  = threadIdx.x;
    const int pair = tid >> 7;
    const int d    = tid & 127;
    const int m    = blockIdx.x * 2 + pair;   // (b,s) row id
    const int b    = m / S_;
    const int s    = m % S_;
    const int len  = lengths[b];

    float p = 0.f;
    if (s < len) {
        const int  blen = basket_len[m];
        const int* it   = items + m * K_;
        for (int k = 0; k < blen; ++k)
            p += encode[(long)it[k] * D_ + d];
        p /= (float)blen;
    }
    pooled[m * D_ + d] = p;
}

// ---------------------------------------------------------------------------
// Kernel G: gx = pooled @ w_ih^T + b_ih. M=12800, N=384, K=128.
// Tiled f32 GEMM: block tile 64M x 128N, Kt=32, 256 thr, 4x8 per-thread tile.
// ---------------------------------------------------------------------------
__global__ __launch_bounds__(256) void gx_gemm_kernel(
    const float* __restrict__ pooled, const float* __restrict__ w_ih,
    const float* __restrict__ b_ih, float* __restrict__ gx)
{
    __shared__ float As[32][64];    // [k][m]
    __shared__ float Bs[32][128];   // [k][n]

    const int tid = threadIdx.x;
    const int bm  = blockIdx.x % 200;
    const int bn  = blockIdx.x / 200;
    const int m0  = bm * 64;
    const int n0  = bn * 128;
    const int tx  = tid & 15;               // -> N
    const int ty  = tid >> 4;               // -> M

    float acc[4][8] = {};

    for (int kt = 0; kt < 128; kt += 32) {
        #pragma unroll
        for (int i = 0; i < 2; ++i) {
            int idx = tid + 256 * i;
            int r = idx >> 3, c = idx & 7;
            float4 v = *reinterpret_cast<const float4*>(
                pooled + (m0 + r) * 128 + kt + c * 4);
            As[c*4+0][r] = v.x; As[c*4+1][r] = v.y;
            As[c*4+2][r] = v.z; As[c*4+3][r] = v.w;
        }
        #pragma unroll
        for (int i = 0; i < 4; ++i) {
            int idx = tid + 256 * i;
            int r = idx >> 3, c = idx & 7;
            float4 v = *reinterpret_cast<const float4*>(
                w_ih + (n0 + r) * 128 + kt + c * 4);
            Bs[c*4+0][r] = v.x; Bs[c*4+1][r] = v.y;
            Bs[c*4+2][r] = v.z; Bs[c*4+3][r] = v.w;
        }
        __syncthreads();

        #pragma unroll
        for (int k = 0; k < 32; ++k) {
            float4 a  = *reinterpret_cast<const float4*>(&As[k][ty * 4]);
            float4 b0 = *reinterpret_cast<const float4*>(&Bs[k][tx * 8]);
            float4 b1 = *reinterpret_cast<const float4*>(&Bs[k][tx * 8 + 4]);
            float av[4] = {a.x, a.y, a.z, a.w};
            float bv[8] = {b0.x, b0.y, b0.z, b0.w, b1.x, b1.y, b1.z, b1.w};
            #pragma unroll
            for (int mi = 0; mi < 4; ++mi)
                #pragma unroll
                for (int ni = 0; ni < 8; ++ni)
                    acc[mi][ni] = fmaf(av[mi], bv[ni], acc[mi][ni]);
        }
        __syncthreads();
    }

    float bias[8];
    #pragma unroll
    for (int ni = 0; ni < 8; ++ni) bias[ni] = b_ih[n0 + tx * 8 + ni];
    #pragma unroll
    for (int mi = 0; mi < 4; ++mi) {
        const int row = m0 + ty * 4 + mi;
        float4 o0, o1;
        o0.x = acc[mi][0] + bias[0]; o0.y = acc[mi][1] + bias[1];
        o0.z = acc[mi][2] + bias[2]; o0.w = acc[mi][3] + bias[3];
        o1.x = acc[mi][4] + bias[4]; o1.y = acc[mi][5] + bias[5];
        o1.z = acc[mi][6] + bias[6]; o1.w = acc[mi][7] + bias[7];
        float* dst = gx + (long)row * G3 + n0 + tx * 8;
        *reinterpret_cast<float4*>(dst)     = o0;
        *reinterpret_cast<float4*>(dst + 4) = o1;
    }
}

// ---------------------------------------------------------------------------
// Kernel B v2: sequential GRU. 256 blocks, 768 threads: TWO threads per
// output row j, each owning HALF of w_hh[j] (64 floats = 16 float4) in VGPRs.
// R7 evidence: 128 floats/thread spilled (VGPR=84 -> 2.5GB L2 restream,
// 64.6us). 64/thread fits the allocator's budget; pair-sum via shfl_xor.
// __launch_bounds__(768,3): 12 waves = 1 block/CU, VGPR cap 168.
// ---------------------------------------------------------------------------
__global__ __launch_bounds__(768, 3) void gru_kernel(
    const int* __restrict__ lengths, const float* __restrict__ w_hh,
    const float* __restrict__ b_hh, const float* __restrict__ h0,
    const float* __restrict__ gx, float* __restrict__ out)
{
    const int b    = blockIdx.x;
    const int len  = lengths[b];
    const int tid  = threadIdx.x;
    const int j    = tid >> 1;     // output row 0..383
    const int half = tid & 1;      // which K-half this thread owns

    // 64 weights -> registers (16 float4), one-time from L2
    float w[64];
    const float4* wrow = reinterpret_cast<const float4*>(w_hh + j * D_ + half * 64);
    #pragma unroll
    for (int q = 0; q < 16; ++q) {
        float4 v = wrow[q];
        w[4*q+0] = v.x; w[4*q+1] = v.y; w[4*q+2] = v.z; w[4*q+3] = v.w;
    }
    #pragma unroll
    for (int i = 0; i < 64; ++i) asm volatile("" : "+v"(w[i]));

    const float bias = half ? 0.f : b_hh[j];   // bias counted once per pair

    __shared__ float4 h4[32];     // hidden state, 128 f32
    __shared__ float  gh[G3];
    if (tid < 128) ((float*)h4)[tid] = h0[b * D_ + tid];
    __syncthreads();

    float* ys = out;                          // (B,S,D)
    float* hu = out + (long)B_ * S_ * D_;     // (B,D)

    const int hbase = half * 16;              // float4 offset into h

    for (int s = 0; s < len; ++s) {
        // issue gx loads early (independent of h) to overlap with the dot
        float gxr = 0.f, gxz = 0.f, gxn = 0.f;
        if (tid < 128) {
            const float* gxp = gx + ((long)b * S_ + s) * G3;
            gxr = gxp[tid]; gxz = gxp[128 + tid]; gxn = gxp[256 + tid];
        }
        // partial dot over this thread's 64-element K-range
        float acc = bias;
        #pragma unroll
        for (int q = 0; q < 16; ++q) {
            float4 hv = h4[hbase + q];
            acc = fmaf(hv.x, w[4*q+0], acc);
            acc = fmaf(hv.y, w[4*q+1], acc);
            acc = fmaf(hv.z, w[4*q+2], acc);
            acc = fmaf(hv.w, w[4*q+3], acc);
        }
        // pair-combine: lanes 2j and 2j+1 are adjacent in the wave
        acc += __shfl_xor(acc, 1);
        gh[j] = acc;                 // both lanes write the same value
        __syncthreads();
        if (tid < 128) {
            float ghr = gh[tid], ghz = gh[128 + tid], ghn = gh[256 + tid];
            float r = 1.f / (1.f + expf(-(gxr + ghr)));
            float z = 1.f / (1.f + expf(-(gxz + ghz)));
            float n = tanhf(gxn + r * ghn);
            float hprev = ((float*)h4)[tid];
            float hn = (1.f - z) * n + z * hprev;
            ys[((long)b * S_ + s) * D_ + tid] = hn;
            ((float*)h4)[tid] = hn;
        }
        __syncthreads();
    }
    if (tid < 128) {
        hu[b * D_ + tid] = ((float*)h4)[tid];
        for (int s = len; s < S_; ++s)
            ys[((long)b * S_ + s) * D_ + tid] = 0.f;
    }
}

extern "C" void kernel_launch(void* const* d_in, const int* in_sizes, int n_in,
                              void* d_out, int out_size, void* d_ws, size_t ws_size,
                              hipStream_t stream) {
    const int*   items      = (const int*)d_in[0];
    const int*   basket_len = (const int*)d_in[1];
    const int*   lengths    = (const int*)d_in[2];
    const float* encode     = (const float*)d_in[3];
    const float* w_ih       = (const float*)d_in[4];
    const float* w_hh       = (const float*)d_in[5];
    const float* b_ih       = (const float*)d_in[6];
    const float* b_hh       = (const float*)d_in[7];
    const float* h0         = (const float*)d_in[8];
    float* out = (float*)d_out;

    float* gx     = (float*)d_ws;                       // 12800*384 f32 = 19.66 MB
    float* pooled = gx + (long)M_ * G3;                 // 12800*128 f32 =  6.55 MB

    pool_kernel<<<M_ / 2, 256, 0, stream>>>(
        items, basket_len, lengths, encode, pooled);
    gx_gemm_kernel<<<600, 256, 0, stream>>>(
        pooled, w_ih, b_ih, gx);
    gru_kernel<<<B_, 768, 0, stream>>>(
        lengths, w_hh, b_hh, h0, gx, out);
}